// Round 3
// baseline (762.740 us; speedup 1.0000x reference)
//
#include <hip/hip_runtime.h>

#define B_ 4
#define T_ 256
#define U_ 64
#define D_ 512    // ENC_DIM == PRED_DIM
#define W_LD 1024 // W leading dim
#define V_ 2048   // VOCAB

#define TT 16     // t rows per block
#define PAD 64    // LDS row stride (floats); 40,960 B/block -> exactly 4 blocks/CU

typedef __attribute__((ext_vector_type(8))) __bf16 bf16x8;
typedef __attribute__((ext_vector_type(4))) float f32x4;

static __device__ inline bf16x8 load8_bf16(const float* __restrict__ p) {
    float4 a = *(const float4*)p;
    float4 b = *(const float4*)(p + 4);
    bf16x8 r;
    r[0] = (__bf16)a.x; r[1] = (__bf16)a.y; r[2] = (__bf16)a.z; r[3] = (__bf16)a.w;
    r[4] = (__bf16)b.x; r[5] = (__bf16)b.y; r[6] = (__bf16)b.z; r[7] = (__bf16)b.w;
    return r;
}

// Fused, monotone-phase: per wave (owns 64-v strip, 16 t-rows, all 64 u):
//   phase 1: enc GEMM (16x64xK) + pred GEMM (64x64xK) -> accumulators
//   phase 2: stage enc(+bias) and pred tiles into wave-private LDS
//   phase 3: pure store stream (LDS reads only -- stores never wait on vmcnt)
// No __syncthreads anywhere (LDS slices are wave-private).
__global__ __launch_bounds__(128) void joint_fused2(
        const float* __restrict__ enc, const float* __restrict__ pred,
        const float* __restrict__ W, const float* __restrict__ bias,
        float* __restrict__ out) {
    const int wave = threadIdx.x >> 6;
    const int lane = threadIdx.x & 63;
    const int quad = lane >> 4;      // 0..3
    const int l16  = lane & 15;

    const int vt = blockIdx.x;       // 0..15  (v-tile of 128)
    const int tb = blockIdx.y;       // 0..15  (t-tile of 16)
    const int b  = blockIdx.z;       // 0..3
    const int t0 = tb * TT;
    const int nbase = vt * 128 + wave * 64;     // wave's global v base

    __shared__ float lds[2 * (TT + 64) * PAD];  // 40,960 B
    float* encS  = lds + wave * (TT + 64) * PAD;  // [TT][PAD]
    float* predS = encS + TT * PAD;               // [64][PAD]

    // ---------------- phase 1a: enc GEMM (16 x 64 x 512) ----------------
    f32x4 eacc[4];
    #pragma unroll
    for (int j = 0; j < 4; ++j) eacc[j] = (f32x4){0.f, 0.f, 0.f, 0.f};
    {
        const float* arow = enc + (size_t)(b * T_ + t0 + l16) * D_;
        #pragma unroll 4
        for (int ks = 0; ks < 16; ++ks) {
            const int k = ks * 32 + quad * 8;
            bf16x8 af = load8_bf16(arow + k);
            #pragma unroll
            for (int j = 0; j < 4; ++j) {
                bf16x8 bfr = load8_bf16(W + (size_t)(nbase + j * 16 + l16) * W_LD + k);
                eacc[j] = __builtin_amdgcn_mfma_f32_16x16x32_bf16(af, bfr, eacc[j], 0, 0, 0);
            }
        }
    }

    // ---------------- phase 1b: pred GEMM (64 x 64 x 512) ----------------
    // W fragment loaded once per (ks,j), reused across 4 u-fragments.
    f32x4 pacc[4][4];   // [h = u-frag][j = v-frag]
    #pragma unroll
    for (int h = 0; h < 4; ++h)
        #pragma unroll
        for (int j = 0; j < 4; ++j) pacc[h][j] = (f32x4){0.f, 0.f, 0.f, 0.f};
    {
        const float* wpred = W + D_;
        const float* prow = pred + (size_t)(b * U_ + l16) * D_;
        #pragma unroll 2
        for (int ks = 0; ks < 16; ++ks) {
            const int k = ks * 32 + quad * 8;
            bf16x8 bfr[4];
            #pragma unroll
            for (int j = 0; j < 4; ++j)
                bfr[j] = load8_bf16(wpred + (size_t)(nbase + j * 16 + l16) * W_LD + k);
            #pragma unroll
            for (int h = 0; h < 4; ++h) {
                bf16x8 af = load8_bf16(prow + (size_t)(h * 16) * D_ + k);
                #pragma unroll
                for (int j = 0; j < 4; ++j)
                    pacc[h][j] = __builtin_amdgcn_mfma_f32_16x16x32_bf16(af, bfr[j], pacc[h][j], 0, 0, 0);
            }
        }
    }

    // ---------------- phase 2: stage into wave-private LDS ----------------
    // C/D layout: col = l16 (v = j*16+l16), row = quad*4 + r
    #pragma unroll
    for (int j = 0; j < 4; ++j) {
        const float bs = bias[nbase + j * 16 + l16];   // bias folded into enc (16 rows)
        #pragma unroll
        for (int r = 0; r < 4; ++r)
            encS[(quad * 4 + r) * PAD + j * 16 + l16] = eacc[j][r] + bs;
    }
    #pragma unroll
    for (int h = 0; h < 4; ++h)
        #pragma unroll
        for (int j = 0; j < 4; ++j)
            #pragma unroll
            for (int r = 0; r < 4; ++r)
                predS[(h * 16 + quad * 4 + r) * PAD + j * 16 + l16] = pacc[h][j][r];

    // ---------------- phase 3: pure store stream ----------------
    // lane covers v = nbase + l16*4 .. +3 ; u = ui*4 + quad, ui = 0..15
    const int vloc = l16 * 4;
    float* outb = out + ((size_t)(b * T_ + t0) * U_ + quad) * V_ + nbase + vloc;
    for (int t = 0; t < TT; ++t) {
        const float4 ev = *(const float4*)(encS + t * PAD + vloc);
        float* orow = outb + (size_t)t * U_ * V_;
        #pragma unroll 16
        for (int ui = 0; ui < 16; ++ui) {
            const float4 pv = *(const float4*)(predS + (ui * 4 + quad) * PAD + vloc);
            float4 o;
            o.x = ev.x + pv.x; o.y = ev.y + pv.y;
            o.z = ev.z + pv.z; o.w = ev.w + pv.w;
            *(float4*)(orow + (size_t)ui * 4 * V_) = o;
        }
    }
}

extern "C" void kernel_launch(void* const* d_in, const int* in_sizes, int n_in,
                              void* d_out, int out_size, void* d_ws, size_t ws_size,
                              hipStream_t stream) {
    const float* enc  = (const float*)d_in[0];
    const float* pred = (const float*)d_in[1];
    const float* W    = (const float*)d_in[2];
    const float* bias = (const float*)d_in[3];
    float* out = (float*)d_out;

    dim3 grid(16, 16, 4);   // (v-tiles, t-tiles, b) -> 1024 blocks, 4/CU, all resident
    joint_fused2<<<grid, dim3(128), 0, stream>>>(enc, pred, W, bias, out);
}